// Round 12
// baseline (279.052 us; speedup 1.0000x reference)
//
#include <hip/hip_runtime.h>
#include <math.h>

#define NN 50000
#define NE 800000
#define ED 128
#define FD 512
#define MAXDEG 64                           // P(Binom(800K,1/50K) > 64) ~ e^-40
#define QKV_BLOCKS (NN / 16)                // 3125
#define SCAT_BLOCKS ((NE + 255) / 256)      // 3125
#define FFN_BLOCKS ((NN + 31) / 32)         // 1563

typedef __attribute__((ext_vector_type(8))) short bf16x8;
typedef __attribute__((ext_vector_type(4))) float f32x4;
typedef _Float16 half2_t __attribute__((ext_vector_type(2)));

static __device__ __forceinline__ float wave_sum(float x) {
#pragma unroll
  for (int off = 32; off > 0; off >>= 1) x += __shfl_xor(x, off, 64);
  return x;
}

static __device__ __forceinline__ unsigned short f2bf(float f) {
  union { float f; unsigned u; } c; c.f = f;
  unsigned r = c.u + 0x7fffu + ((c.u >> 16) & 1u);
  return (unsigned short)(r >> 16);
}

static __device__ __forceinline__ unsigned short f2h(float f) {
  union { _Float16 h; unsigned short u; } c; c.h = (_Float16)f;
  return c.u;
}

static __device__ __forceinline__ half2_t u2h2(unsigned u) {
  union { unsigned u; half2_t h; } c; c.u = u;
  return c.h;
}

#if __has_builtin(__builtin_amdgcn_fdot2)
#define FDOT2(a, b, c) __builtin_amdgcn_fdot2((a), (b), (c), false)
#else
static __device__ __forceinline__ float FDOT2(half2_t a, half2_t b, float c) {
  return (float)a[0] * (float)b[0] + (float)a[1] * (float)b[1] + c;
}
#endif

// ---- one-time weight swizzle to fragment-major bf16 + cursor zero ----
__global__ void k_prep(const float* __restrict__ Wqkv, const float* __restrict__ W1,
                       const float* __restrict__ W2, unsigned short* __restrict__ WqkvF,
                       unsigned short* __restrict__ W1F, unsigned short* __restrict__ W2F,
                       int* __restrict__ cursor) {
  int idx = blockIdx.x * 256 + threadIdx.x;  // 65536 threads
  if (idx < NN) cursor[idx] = 0;
  if (idx < 49152) {  // WqkvF: t<24, kb<4
    int j = idx & 7, l = (idx >> 3) & 63, kb = (idx >> 9) & 3, t = idx >> 11;
    int k = kb * 32 + (l >> 4) * 8 + j, n = t * 16 + (l & 15);
    WqkvF[idx] = f2bf(Wqkv[k * 384 + n]);
  }
  {  // W1F: t<32, kb<4
    int j = idx & 7, l = (idx >> 3) & 63, kb = (idx >> 9) & 3, t = idx >> 11;
    int k = kb * 32 + (l >> 4) * 8 + j, n = t * 16 + (l & 15);
    W1F[idx] = f2bf(W1[k * 512 + n]);
  }
  {  // W2F: t<8, kb<16
    int j = idx & 7, l = (idx >> 3) & 63, kb = (idx >> 9) & 15, t = idx >> 13;
    int k = kb * 32 + (l >> 4) * 8 + j, n = t * 16 + (l & 15);
    W2F[idx] = f2bf(W2[k * 128 + n]);
  }
}

// ---- fused: QKV GEMM + padded-CSR scatter ----
// Scatter (blocks >= QKV_BLOCKS) is pure atomic latency (VALUBusy 0.2%);
// running it concurrently with the streaming GEMM hides the smaller of the
// two (~20us). q f16 pre-scaled by 128^-0.5; kv row: K f16 [0,128),
// V f16 [128,256) per node (one 512B region per edge).
__global__ __launch_bounds__(256) void k_qkv_scat(
    const float* __restrict__ X, const unsigned short* __restrict__ WqkvF,
    const float* __restrict__ B, unsigned short* __restrict__ q,
    unsigned short* __restrict__ kv, const int* __restrict__ src,
    const int* __restrict__ dst, int* __restrict__ cursor,
    int* __restrict__ colidx) {
  __shared__ unsigned short xs[16][136];
  const int tid = threadIdx.x;
  if (blockIdx.x >= QKV_BLOCKS) {
    const int e = (blockIdx.x - QKV_BLOCKS) * 256 + tid;
    if (e < NE) {
      const int s = src[e];
      const int d = dst[e];
      const int slot = atomicAdd(&cursor[s], 1);
      if (slot < MAXDEG) colidx[s * MAXDEG + slot] = d;
    }
    return;
  }
  const int row0 = blockIdx.x * 16;
  for (int idx = tid; idx < 512; idx += 256) {
    int r = idx >> 5, c4 = (idx & 31) << 2;
    float4 val = *(const float4*)&X[(size_t)(row0 + r) * ED + c4];
    xs[r][c4] = f2bf(val.x); xs[r][c4 + 1] = f2bf(val.y);
    xs[r][c4 + 2] = f2bf(val.z); xs[r][c4 + 3] = f2bf(val.w);
  }
  __syncthreads();
  const int wv = tid >> 6, lane = tid & 63;
  const int ln = lane & 15, quad = lane >> 4;
  const int koff = quad * 8;
  bf16x8 a[4];
#pragma unroll
  for (int kb = 0; kb < 4; kb++) a[kb] = *(const bf16x8*)&xs[ln][kb * 32 + koff];
  for (int g = 0; g < 3; g++) {
    const int t0 = wv * 6 + g * 2;
    bf16x8 b[2][4];
#pragma unroll
    for (int j = 0; j < 2; j++)
#pragma unroll
      for (int kb = 0; kb < 4; kb++)
        b[j][kb] = *(const bf16x8*)&WqkvF[(size_t)(((t0 + j) * 4 + kb) * 64 + lane) * 8];
    f32x4 acc[2];
#pragma unroll
    for (int j = 0; j < 2; j++) acc[j] = (f32x4){0.f, 0.f, 0.f, 0.f};
#pragma unroll
    for (int kb = 0; kb < 4; kb++)
#pragma unroll
      for (int j = 0; j < 2; j++)
        acc[j] = __builtin_amdgcn_mfma_f32_16x16x32_bf16(a[kb], b[j][kb], acc[j], 0, 0, 0);
#pragma unroll
    for (int j = 0; j < 2; j++) {
      const int col = (t0 + j) * 16 + ln;
      const float bias = B[col];
      if (col < 128) {
#pragma unroll
        for (int r = 0; r < 4; r++)
          q[(size_t)(row0 + quad * 4 + r) * ED + col] =
              f2h((acc[j][r] + bias) * 0.08838834764831845f);  // 128^-0.5
      } else {
        // both K (col 128..255) and V (col 256..383) land at kv[row*256 + col-128]
#pragma unroll
        for (int r = 0; r < 4; r++)
          kv[(size_t)(row0 + quad * 4 + r) * 256 + (col - 128)] = f2h(acc[j][r] + bias);
      }
    }
  }
}

// ---- attention chunk (f16 packed math, r5-proven) ----
template <bool FULL>
static __device__ __forceinline__ void attn_chunk(
    int base, int cnt, int grp, int gl, int lane, const half2_t* qh,
    const unsigned short* __restrict__ kv, const int* __restrict__ colidx,
    float& l, half2_t* axh) {
  const int C = FULL ? 16 : cnt;
  int colreg = 0;
  if (lane < C) colreg = colidx[base + lane];
  const int itmax = FULL ? 4 : ((C + 3) >> 2);
#pragma unroll(FULL ? 4 : 1)
  for (int it = 0; it < itmax; it++) {
    const int t = it * 4 + grp;
    const bool act = FULL || t < C;
    // inactive lanes re-load slot 0's row (valid, cache-hot, masked by e=0)
    const int cc = __shfl(colreg, act ? t : 0, 64);
    const unsigned short* row = &kv[(size_t)cc * 256 + gl * 8];
    uint4 kw = *(const uint4*)row;
    uint4 vw = *(const uint4*)(row + 128);  // imm offset:256 off same base
    float dot = FDOT2(qh[0], u2h2(kw.x), 0.f);
    dot = FDOT2(qh[1], u2h2(kw.y), dot);
    dot = FDOT2(qh[2], u2h2(kw.z), dot);
    dot = FDOT2(qh[3], u2h2(kw.w), dot);
    dot += __shfl_xor(dot, 1, 64);
    dot += __shfl_xor(dot, 2, 64);
    dot += __shfl_xor(dot, 4, 64);
    dot += __shfl_xor(dot, 8, 64);
    const float e = act ? __expf(dot) : 0.f;  // q pre-scaled by 128^-0.5
    l += e;
    const half2_t e2 = {(_Float16)e, (_Float16)e};
    axh[0] += e2 * u2h2(vw.x);
    axh[1] += e2 * u2h2(vw.y);
    axh[2] += e2 * u2h2(vw.z);
    axh[3] += e2 * u2h2(vw.w);
  }
}

// ---- attention on padded CSR: att = x + attn, stored f16 ----
__global__ __launch_bounds__(256) void k_attn(
    const unsigned short* __restrict__ q, const unsigned short* __restrict__ kv,
    const float* __restrict__ x, const int* __restrict__ cursor,
    const int* __restrict__ colidx, unsigned short* __restrict__ attb) {
  const int wv = threadIdx.x >> 6;
  const int lane = threadIdx.x & 63;
  const int grp = lane >> 4, gl = lane & 15;
  const int node = blockIdx.x * 4 + wv;  // NN % 4 == 0

  half2_t qh[4];
  {
    uint4 qw = *(const uint4*)&q[(size_t)node * ED + gl * 8];
    qh[0] = u2h2(qw.x); qh[1] = u2h2(qw.y);
    qh[2] = u2h2(qw.z); qh[3] = u2h2(qw.w);
  }
  const int cnt0 = cursor[node];
  const int cnt = cnt0 > MAXDEG ? MAXDEG : cnt0;
  const int b0 = node * MAXDEG;
  float l = 0.f;
  half2_t axh[4] = {};
  int off = 0;
  for (; off + 16 <= cnt; off += 16)
    attn_chunk<true>(b0 + off, 16, grp, gl, lane, qh, kv, colidx, l, axh);
  if (off < cnt)
    attn_chunk<false>(b0 + off, cnt - off, grp, gl, lane, qh, kv, colidx, l, axh);

  // cross-group reduction: groups hold disjoint edge subsets (packed halves)
#pragma unroll
  for (int j = 0; j < 4; j++) {
    union { half2_t h; int i; } c;
    union { int i; half2_t h; } d;
    c.h = axh[j]; d.i = __shfl_xor(c.i, 16, 64); axh[j] += d.h;
    c.h = axh[j]; d.i = __shfl_xor(c.i, 32, 64); axh[j] += d.h;
  }
  l += __shfl_xor(l, 16, 64);
  l += __shfl_xor(l, 32, 64);

  const float inv = (cnt > 0) ? 1.0f / l : 0.f;
  // this lane outputs dims d0, d0+1 (dims partitioned uniquely over 64 lanes)
  const int d0 = gl * 8 + grp * 2;
  const half2_t s = (grp == 0) ? axh[0] : (grp == 1) ? axh[1] : (grp == 2) ? axh[2] : axh[3];
  float2 xv = *(const float2*)&x[(size_t)node * ED + d0];
  unsigned pk = (unsigned)f2h(xv.x + (float)s[0] * inv) |
                ((unsigned)f2h(xv.y + (float)s[1] * inv) << 16);
  *(unsigned*)&attb[(size_t)node * ED + d0] = pk;
}

// ---- FFN via MFMA, 32 rows/block: LN1 + FFN + residual + LN2 ----
// 32-row M-tile halves L2 weight re-reads (819->410 MB total): each b
// fragment now feeds 2 MFMAs (row-halves lo=rows 0-15, hi=rows 16-31).
// LDS 58.9KB -> 2 blocks/CU. Last block has 16 valid rows (guarded).
__global__ __launch_bounds__(256) void k_ffn_ln2(
    const unsigned short* __restrict__ attb, const unsigned short* __restrict__ W1F,
    const float* __restrict__ b1, const unsigned short* __restrict__ W2F,
    const float* __restrict__ b2, const float* __restrict__ g1,
    const float* __restrict__ be1, const float* __restrict__ g2,
    const float* __restrict__ be2, float* __restrict__ out) {
  __shared__ unsigned short xs[32][136];
  __shared__ unsigned short hs[32][520];  // later aliased ys f32[32][132]
  __shared__ float ysf[32][132];          // LN1 output f32 (residual source)
  float* ys = (float*)&hs[0][0];
  const int row0 = blockIdx.x * 32;
  const int tid = threadIdx.x;
  // stage att f16 -> ysf f32: 512 uint4 loads, 2/thread; pad rows with 0
  for (int i = tid; i < 512; i += 256) {
    const int r = i >> 4, c8 = (i & 15) << 3;
    const int row = row0 + r;
    if (row < NN) {
      uint4 aw = *(const uint4*)&attb[(size_t)row * ED + c8];
      half2_t h0 = u2h2(aw.x), h1 = u2h2(aw.y), h2 = u2h2(aw.z), h3 = u2h2(aw.w);
      ysf[r][c8] = (float)h0[0];     ysf[r][c8 + 1] = (float)h0[1];
      ysf[r][c8 + 2] = (float)h1[0]; ysf[r][c8 + 3] = (float)h1[1];
      ysf[r][c8 + 4] = (float)h2[0]; ysf[r][c8 + 5] = (float)h2[1];
      ysf[r][c8 + 6] = (float)h3[0]; ysf[r][c8 + 7] = (float)h3[1];
    } else {
#pragma unroll
      for (int k = 0; k < 8; k++) ysf[r][c8 + k] = 0.f;
    }
  }
  __syncthreads();
  const int wv = tid >> 6, lane = tid & 63;
  // LN1: each wave handles 8 rows in 4 passes (2 rows/pass, 32 lanes/row,
  // 4 dims/lane): r = wv*8 + pass*2 + (lane>>5) covers all 32 rows.
#pragma unroll
  for (int pass = 0; pass < 4; pass++) {
    const int r = wv * 8 + pass * 2 + (lane >> 5);
    const int hd = (lane & 31) << 2;
    float4 vv = *(const float4*)&ysf[r][hd];
    float s4 = vv.x + vv.y + vv.z + vv.w;
#pragma unroll
    for (int off = 16; off > 0; off >>= 1) s4 += __shfl_xor(s4, off, 64);
    const float mean = s4 * (1.f / ED);
    const float dx0 = vv.x - mean, dx1 = vv.y - mean, dx2 = vv.z - mean, dx3 = vv.w - mean;
    float vr = dx0 * dx0 + dx1 * dx1 + dx2 * dx2 + dx3 * dx3;
#pragma unroll
    for (int off = 16; off > 0; off >>= 1) vr += __shfl_xor(vr, off, 64);
    const float rstd = rsqrtf(vr * (1.f / ED) + 1e-5f);
    const float4 gg = *(const float4*)&g1[hd];
    const float4 bb = *(const float4*)&be1[hd];
    const float o0 = dx0 * rstd * gg.x + bb.x;
    const float o1 = dx1 * rstd * gg.y + bb.y;
    const float o2 = dx2 * rstd * gg.z + bb.z;
    const float o3 = dx3 * rstd * gg.w + bb.w;
    xs[r][hd] = f2bf(o0); xs[r][hd + 1] = f2bf(o1);
    xs[r][hd + 2] = f2bf(o2); xs[r][hd + 3] = f2bf(o3);
    *(float4*)&ysf[r][hd] = make_float4(o0, o1, o2, o3);
  }
  __syncthreads();
  const int ln = lane & 15, quad = lane >> 4;
  const int koff = quad * 8;
  bf16x8 a1lo[4], a1hi[4];
#pragma unroll
  for (int kb = 0; kb < 4; kb++) {
    a1lo[kb] = *(const bf16x8*)&xs[ln][kb * 32 + koff];
    a1hi[kb] = *(const bf16x8*)&xs[16 + ln][kb * 32 + koff];
  }
  for (int g = 0; g < 4; g++) {
    const int t0 = wv * 8 + g * 2;
    bf16x8 b[2][4];
#pragma unroll
    for (int j = 0; j < 2; j++)
#pragma unroll
      for (int kb = 0; kb < 4; kb++)
        b[j][kb] = *(const bf16x8*)&W1F[(size_t)(((t0 + j) * 4 + kb) * 64 + lane) * 8];
    f32x4 acc[2][2];  // [j][half]
#pragma unroll
    for (int j = 0; j < 2; j++)
#pragma unroll
      for (int h = 0; h < 2; h++) acc[j][h] = (f32x4){0.f, 0.f, 0.f, 0.f};
#pragma unroll
    for (int kb = 0; kb < 4; kb++)
#pragma unroll
      for (int j = 0; j < 2; j++) {
        acc[j][0] = __builtin_amdgcn_mfma_f32_16x16x32_bf16(a1lo[kb], b[j][kb], acc[j][0], 0, 0, 0);
        acc[j][1] = __builtin_amdgcn_mfma_f32_16x16x32_bf16(a1hi[kb], b[j][kb], acc[j][1], 0, 0, 0);
      }
#pragma unroll
    for (int j = 0; j < 2; j++) {
      const int col = (t0 + j) * 16 + ln;
      const float bias = b1[col];
#pragma unroll
      for (int r = 0; r < 4; r++) {
        hs[quad * 4 + r][col] = f2bf(fmaxf(acc[j][0][r] + bias, 0.f));
        hs[16 + quad * 4 + r][col] = f2bf(fmaxf(acc[j][1][r] + bias, 0.f));
      }
    }
  }
  __syncthreads();
  f32x4 acc2[2][2];  // [nt][half]
#pragma unroll
  for (int nt = 0; nt < 2; nt++)
#pragma unroll
    for (int h = 0; h < 2; h++) acc2[nt][h] = (f32x4){0.f, 0.f, 0.f, 0.f};
  const int nt0 = wv * 2;
  for (int kg = 0; kg < 4; kg++) {
    bf16x8 alo[4], ahi[4];
#pragma unroll
    for (int kk = 0; kk < 4; kk++) {
      alo[kk] = *(const bf16x8*)&hs[ln][(kg * 4 + kk) * 32 + koff];
      ahi[kk] = *(const bf16x8*)&hs[16 + ln][(kg * 4 + kk) * 32 + koff];
    }
    bf16x8 b[2][4];
#pragma unroll
    for (int nt = 0; nt < 2; nt++)
#pragma unroll
      for (int kk = 0; kk < 4; kk++)
        b[nt][kk] = *(const bf16x8*)&W2F[(size_t)(((nt0 + nt) * 16 + kg * 4 + kk) * 64 + lane) * 8];
#pragma unroll
    for (int kk = 0; kk < 4; kk++)
#pragma unroll
      for (int nt = 0; nt < 2; nt++) {
        acc2[nt][0] = __builtin_amdgcn_mfma_f32_16x16x32_bf16(alo[kk], b[nt][kk], acc2[nt][0], 0, 0, 0);
        acc2[nt][1] = __builtin_amdgcn_mfma_f32_16x16x32_bf16(ahi[kk], b[nt][kk], acc2[nt][1], 0, 0, 0);
      }
  }
  __syncthreads();
#pragma unroll
  for (int nt = 0; nt < 2; nt++) {
    const int col = (nt0 + nt) * 16 + ln;
    const float bias = b2[col];
#pragma unroll
    for (int r = 0; r < 4; r++) {
      ys[(quad * 4 + r) * 132 + col] = acc2[nt][0][r] + bias;
      ys[(16 + quad * 4 + r) * 132 + col] = acc2[nt][1][r] + bias;
    }
  }
  __syncthreads();
  float2 gg = *(const float2*)&g2[2 * lane];
  float2 bbe = *(const float2*)&be2[2 * lane];
#pragma unroll
  for (int rr = 0; rr < 8; rr++) {
    const int r = wv * 8 + rr;
    const int row = row0 + r;
    float vx = ys[r * 132 + 2 * lane] + ysf[r][2 * lane];
    float vy = ys[r * 132 + 2 * lane + 1] + ysf[r][2 * lane + 1];
    float mean = wave_sum(vx + vy) * (1.f / ED);
    float dx = vx - mean, dy = vy - mean;
    float var = wave_sum(dx * dx + dy * dy) * (1.f / ED);
    float rstd = rsqrtf(var + 1e-5f);
    if (row < NN) {
      float2 o = make_float2(dx * rstd * gg.x + bbe.x, dy * rstd * gg.y + bbe.y);
      *(float2*)&out[(size_t)row * ED + 2 * lane] = o;
    }
  }
}

extern "C" void kernel_launch(void* const* d_in, const int* in_sizes, int n_in,
                              void* d_out, int out_size, void* d_ws, size_t ws_size,
                              hipStream_t stream) {
  const float* x = (const float*)d_in[0];
  const int* ei = (const int*)d_in[1];
  const float* W_qkv = (const float*)d_in[2];
  const float* b_qkv = (const float*)d_in[3];
  const float* W1 = (const float*)d_in[4];
  const float* b1 = (const float*)d_in[5];
  const float* W2 = (const float*)d_in[6];
  const float* b2 = (const float*)d_in[7];
  const float* g1 = (const float*)d_in[8];
  const float* be1 = (const float*)d_in[9];
  const float* g2 = (const float*)d_in[10];
  const float* be2 = (const float*)d_in[11];
  float* out = (float*)d_out;

  char* ws = (char*)d_ws;
  size_t off = 0;
  auto alloc = [&](size_t bytes) -> char* {
    char* p = ws + off;
    off = (off + bytes + 255) & ~(size_t)255;
    return p;
  };
  unsigned short* q = (unsigned short*)alloc(2 * (size_t)NN * ED);
  unsigned short* kv = (unsigned short*)alloc(2 * (size_t)NN * 256);
  unsigned short* attb = (unsigned short*)alloc(2 * (size_t)NN * ED);
  unsigned short* WqkvF = (unsigned short*)alloc(2 * 24 * 4 * 64 * 8);
  unsigned short* W1F = (unsigned short*)alloc(2 * 32 * 4 * 64 * 8);
  unsigned short* W2F = (unsigned short*)alloc(2 * 8 * 16 * 64 * 8);
  int* cursor = (int*)alloc(sizeof(int) * NN);
  int* colidx = (int*)alloc(sizeof(int) * (size_t)NN * MAXDEG);

  k_prep<<<256, 256, 0, stream>>>(W_qkv, W1, W2, WqkvF, W1F, W2F, cursor);
  k_qkv_scat<<<QKV_BLOCKS + SCAT_BLOCKS, 256, 0, stream>>>(x, WqkvF, b_qkv, q, kv,
                                                           ei, ei + NE, cursor, colidx);
  k_attn<<<NN / 4, 256, 0, stream>>>(q, kv, x, cursor, colidx, attb);
  k_ffn_ln2<<<FFN_BLOCKS, 256, 0, stream>>>(attb, W1F, b1, W2F, b2, g1, be1, g2, be2, out);
}

// Round 13
// 242.420 us; speedup vs baseline: 1.1511x; 1.1511x over previous
//
#include <hip/hip_runtime.h>
#include <math.h>

#define NN 50000
#define NE 800000
#define ED 128
#define FD 512
#define MAXDEG 64                           // P(Binom(800K,1/50K) > 64) ~ e^-40
#define QKV_BLOCKS (NN / 16)                // 3125
#define SCAT_BLOCKS ((NE + 255) / 256)      // 3125

typedef __attribute__((ext_vector_type(8))) short bf16x8;
typedef __attribute__((ext_vector_type(4))) float f32x4;
typedef _Float16 half2_t __attribute__((ext_vector_type(2)));

static __device__ __forceinline__ float wave_sum(float x) {
#pragma unroll
  for (int off = 32; off > 0; off >>= 1) x += __shfl_xor(x, off, 64);
  return x;
}

static __device__ __forceinline__ unsigned short f2bf(float f) {
  union { float f; unsigned u; } c; c.f = f;
  unsigned r = c.u + 0x7fffu + ((c.u >> 16) & 1u);
  return (unsigned short)(r >> 16);
}

static __device__ __forceinline__ unsigned short f2h(float f) {
  union { _Float16 h; unsigned short u; } c; c.h = (_Float16)f;
  return c.u;
}

static __device__ __forceinline__ half2_t u2h2(unsigned u) {
  union { unsigned u; half2_t h; } c; c.u = u;
  return c.h;
}

#if __has_builtin(__builtin_amdgcn_fdot2)
#define FDOT2(a, b, c) __builtin_amdgcn_fdot2((a), (b), (c), false)
#else
static __device__ __forceinline__ float FDOT2(half2_t a, half2_t b, float c) {
  return (float)a[0] * (float)b[0] + (float)a[1] * (float)b[1] + c;
}
#endif

// ---- one-time weight swizzle to fragment-major bf16 + cursor zero ----
__global__ void k_prep(const float* __restrict__ Wqkv, const float* __restrict__ W1,
                       const float* __restrict__ W2, unsigned short* __restrict__ WqkvF,
                       unsigned short* __restrict__ W1F, unsigned short* __restrict__ W2F,
                       int* __restrict__ cursor) {
  int idx = blockIdx.x * 256 + threadIdx.x;  // 65536 threads
  if (idx < NN) cursor[idx] = 0;
  if (idx < 49152) {  // WqkvF: t<24, kb<4
    int j = idx & 7, l = (idx >> 3) & 63, kb = (idx >> 9) & 3, t = idx >> 11;
    int k = kb * 32 + (l >> 4) * 8 + j, n = t * 16 + (l & 15);
    WqkvF[idx] = f2bf(Wqkv[k * 384 + n]);
  }
  {  // W1F: t<32, kb<4
    int j = idx & 7, l = (idx >> 3) & 63, kb = (idx >> 9) & 3, t = idx >> 11;
    int k = kb * 32 + (l >> 4) * 8 + j, n = t * 16 + (l & 15);
    W1F[idx] = f2bf(W1[k * 512 + n]);
  }
  {  // W2F: t<8, kb<16
    int j = idx & 7, l = (idx >> 3) & 63, kb = (idx >> 9) & 15, t = idx >> 13;
    int k = kb * 32 + (l >> 4) * 8 + j, n = t * 16 + (l & 15);
    W2F[idx] = f2bf(W2[k * 128 + n]);
  }
}

// ---- fused QKV GEMM + scatter, BLOCK-PARITY interleaved ----
// r11 lesson: appending scatter blocks AFTER the GEMM blocks serialized them
// (dispatch order) -> 95us. Parity split co-schedules both populations from
// cycle 0: even blocks stream the GEMM (BW-bound), odd blocks run the atomic
// scatter (latency-bound, VALUBusy 0.2%) underneath it.
__global__ __launch_bounds__(256) void k_qkv_scat(
    const float* __restrict__ X, const unsigned short* __restrict__ WqkvF,
    const float* __restrict__ B, unsigned short* __restrict__ q,
    unsigned short* __restrict__ kv, const int* __restrict__ src,
    const int* __restrict__ dst, int* __restrict__ cursor,
    int* __restrict__ colidx) {
  __shared__ unsigned short xs[16][136];
  const int tid = threadIdx.x;
  if (blockIdx.x & 1) {  // scatter half: odd blocks
    const int e = (blockIdx.x >> 1) * 256 + tid;
    if (e < NE) {
      const int s = src[e];
      const int d = dst[e];
      const int slot = atomicAdd(&cursor[s], 1);
      if (slot < MAXDEG) colidx[s * MAXDEG + slot] = d;
    }
    return;
  }
  const int row0 = (blockIdx.x >> 1) * 16;
  for (int idx = tid; idx < 512; idx += 256) {
    int r = idx >> 5, c4 = (idx & 31) << 2;
    float4 val = *(const float4*)&X[(size_t)(row0 + r) * ED + c4];
    xs[r][c4] = f2bf(val.x); xs[r][c4 + 1] = f2bf(val.y);
    xs[r][c4 + 2] = f2bf(val.z); xs[r][c4 + 3] = f2bf(val.w);
  }
  __syncthreads();
  const int wv = tid >> 6, lane = tid & 63;
  const int ln = lane & 15, quad = lane >> 4;
  const int koff = quad * 8;
  bf16x8 a[4];
#pragma unroll
  for (int kb = 0; kb < 4; kb++) a[kb] = *(const bf16x8*)&xs[ln][kb * 32 + koff];
  for (int g = 0; g < 3; g++) {
    const int t0 = wv * 6 + g * 2;
    bf16x8 b[2][4];
#pragma unroll
    for (int j = 0; j < 2; j++)
#pragma unroll
      for (int kb = 0; kb < 4; kb++)
        b[j][kb] = *(const bf16x8*)&WqkvF[(size_t)(((t0 + j) * 4 + kb) * 64 + lane) * 8];
    f32x4 acc[2];
#pragma unroll
    for (int j = 0; j < 2; j++) acc[j] = (f32x4){0.f, 0.f, 0.f, 0.f};
#pragma unroll
    for (int kb = 0; kb < 4; kb++)
#pragma unroll
      for (int j = 0; j < 2; j++)
        acc[j] = __builtin_amdgcn_mfma_f32_16x16x32_bf16(a[kb], b[j][kb], acc[j], 0, 0, 0);
#pragma unroll
    for (int j = 0; j < 2; j++) {
      const int col = (t0 + j) * 16 + ln;
      const float bias = B[col];
      if (col < 128) {
#pragma unroll
        for (int r = 0; r < 4; r++)
          q[(size_t)(row0 + quad * 4 + r) * ED + col] =
              f2h((acc[j][r] + bias) * 0.08838834764831845f);  // 128^-0.5
      } else {
        // both K (col 128..255) and V (col 256..383) land at kv[row*256 + col-128]
#pragma unroll
        for (int r = 0; r < 4; r++)
          kv[(size_t)(row0 + quad * 4 + r) * 256 + (col - 128)] = f2h(acc[j][r] + bias);
      }
    }
  }
}

// ---- attention chunk (f16 packed math, r5-proven) ----
template <bool FULL>
static __device__ __forceinline__ void attn_chunk(
    int base, int cnt, int grp, int gl, int lane, const half2_t* qh,
    const unsigned short* __restrict__ kv, const int* __restrict__ colidx,
    float& l, half2_t* axh) {
  const int C = FULL ? 16 : cnt;
  int colreg = 0;
  if (lane < C) colreg = colidx[base + lane];
  const int itmax = FULL ? 4 : ((C + 3) >> 2);
#pragma unroll(FULL ? 4 : 1)
  for (int it = 0; it < itmax; it++) {
    const int t = it * 4 + grp;
    const bool act = FULL || t < C;
    // inactive lanes re-load slot 0's row (valid, cache-hot, masked by e=0)
    const int cc = __shfl(colreg, act ? t : 0, 64);
    const unsigned short* row = &kv[(size_t)cc * 256 + gl * 8];
    uint4 kw = *(const uint4*)row;
    uint4 vw = *(const uint4*)(row + 128);  // imm offset:256 off same base
    float dot = FDOT2(qh[0], u2h2(kw.x), 0.f);
    dot = FDOT2(qh[1], u2h2(kw.y), dot);
    dot = FDOT2(qh[2], u2h2(kw.z), dot);
    dot = FDOT2(qh[3], u2h2(kw.w), dot);
    dot += __shfl_xor(dot, 1, 64);
    dot += __shfl_xor(dot, 2, 64);
    dot += __shfl_xor(dot, 4, 64);
    dot += __shfl_xor(dot, 8, 64);
    const float e = act ? __expf(dot) : 0.f;  // q pre-scaled by 128^-0.5
    l += e;
    const half2_t e2 = {(_Float16)e, (_Float16)e};
    axh[0] += e2 * u2h2(vw.x);
    axh[1] += e2 * u2h2(vw.y);
    axh[2] += e2 * u2h2(vw.z);
    axh[3] += e2 * u2h2(vw.w);
  }
}

// ---- attention on padded CSR: att = x + attn, stored f16 ----
__global__ __launch_bounds__(256) void k_attn(
    const unsigned short* __restrict__ q, const unsigned short* __restrict__ kv,
    const float* __restrict__ x, const int* __restrict__ cursor,
    const int* __restrict__ colidx, unsigned short* __restrict__ attb) {
  const int wv = threadIdx.x >> 6;
  const int lane = threadIdx.x & 63;
  const int grp = lane >> 4, gl = lane & 15;
  const int node = blockIdx.x * 4 + wv;  // NN % 4 == 0

  half2_t qh[4];
  {
    uint4 qw = *(const uint4*)&q[(size_t)node * ED + gl * 8];
    qh[0] = u2h2(qw.x); qh[1] = u2h2(qw.y);
    qh[2] = u2h2(qw.z); qh[3] = u2h2(qw.w);
  }
  const int cnt0 = cursor[node];
  const int cnt = cnt0 > MAXDEG ? MAXDEG : cnt0;
  const int b0 = node * MAXDEG;
  float l = 0.f;
  half2_t axh[4] = {};
  int off = 0;
  for (; off + 16 <= cnt; off += 16)
    attn_chunk<true>(b0 + off, 16, grp, gl, lane, qh, kv, colidx, l, axh);
  if (off < cnt)
    attn_chunk<false>(b0 + off, cnt - off, grp, gl, lane, qh, kv, colidx, l, axh);

  // cross-group reduction: groups hold disjoint edge subsets (packed halves)
#pragma unroll
  for (int j = 0; j < 4; j++) {
    union { half2_t h; int i; } c;
    union { int i; half2_t h; } d;
    c.h = axh[j]; d.i = __shfl_xor(c.i, 16, 64); axh[j] += d.h;
    c.h = axh[j]; d.i = __shfl_xor(c.i, 32, 64); axh[j] += d.h;
  }
  l += __shfl_xor(l, 16, 64);
  l += __shfl_xor(l, 32, 64);

  const float inv = (cnt > 0) ? 1.0f / l : 0.f;
  // this lane outputs dims d0, d0+1 (dims partitioned uniquely over 64 lanes)
  const int d0 = gl * 8 + grp * 2;
  const half2_t s = (grp == 0) ? axh[0] : (grp == 1) ? axh[1] : (grp == 2) ? axh[2] : axh[3];
  float2 xv = *(const float2*)&x[(size_t)node * ED + d0];
  unsigned pk = (unsigned)f2h(xv.x + (float)s[0] * inv) |
                ((unsigned)f2h(xv.y + (float)s[1] * inv) << 16);
  *(unsigned*)&attb[(size_t)node * ED + d0] = pk;
}

// ---- FFN via MFMA: LN1 (fused at staging) + FFN + residual + LN2 ----
// in: att f16 (x + attn); out: final f32   (r10-proven 16-row version)
__global__ __launch_bounds__(256) void k_ffn_ln2(
    const unsigned short* __restrict__ attb, const unsigned short* __restrict__ W1F,
    const float* __restrict__ b1, const unsigned short* __restrict__ W2F,
    const float* __restrict__ b2, const float* __restrict__ g1,
    const float* __restrict__ be1, const float* __restrict__ g2,
    const float* __restrict__ be2, float* __restrict__ out) {
  __shared__ unsigned short xs[16][136];
  __shared__ unsigned short hs[16][520];  // later aliased ys f32[16][132]
  __shared__ float ysf[16][132];          // LN1 output f32 (residual source)
  float* ys = (float*)&hs[0][0];
  const int row0 = blockIdx.x * 16;
  const int tid = threadIdx.x;
  {  // stage att f16 -> ysf f32: tid covers 8 halves (16B)
    const int r = tid >> 4, c8 = (tid & 15) << 3;
    uint4 aw = *(const uint4*)&attb[(size_t)(row0 + r) * ED + c8];
    half2_t h0 = u2h2(aw.x), h1 = u2h2(aw.y), h2 = u2h2(aw.z), h3 = u2h2(aw.w);
    ysf[r][c8] = (float)h0[0];     ysf[r][c8 + 1] = (float)h0[1];
    ysf[r][c8 + 2] = (float)h1[0]; ysf[r][c8 + 3] = (float)h1[1];
    ysf[r][c8 + 4] = (float)h2[0]; ysf[r][c8 + 5] = (float)h2[1];
    ysf[r][c8 + 6] = (float)h3[0]; ysf[r][c8 + 7] = (float)h3[1];
  }
  __syncthreads();
  const int wv = tid >> 6, lane = tid & 63;
  // LN1: each wave handles 4 rows in two passes (2 rows/pass, 32 lanes/row,
  // 4 dims/lane); covers all 16 rows: r = wv*4 + half*2 + (lane>>5).
#pragma unroll
  for (int half = 0; half < 2; half++) {
    const int r = wv * 4 + half * 2 + (lane >> 5);
    const int hd = (lane & 31) << 2;
    float4 vv = *(const float4*)&ysf[r][hd];
    float s4 = vv.x + vv.y + vv.z + vv.w;
#pragma unroll
    for (int off = 16; off > 0; off >>= 1) s4 += __shfl_xor(s4, off, 64);
    const float mean = s4 * (1.f / ED);
    const float dx0 = vv.x - mean, dx1 = vv.y - mean, dx2 = vv.z - mean, dx3 = vv.w - mean;
    float vr = dx0 * dx0 + dx1 * dx1 + dx2 * dx2 + dx3 * dx3;
#pragma unroll
    for (int off = 16; off > 0; off >>= 1) vr += __shfl_xor(vr, off, 64);
    const float rstd = rsqrtf(vr * (1.f / ED) + 1e-5f);
    const float4 gg = *(const float4*)&g1[hd];
    const float4 bb = *(const float4*)&be1[hd];
    const float o0 = dx0 * rstd * gg.x + bb.x;
    const float o1 = dx1 * rstd * gg.y + bb.y;
    const float o2 = dx2 * rstd * gg.z + bb.z;
    const float o3 = dx3 * rstd * gg.w + bb.w;
    xs[r][hd] = f2bf(o0); xs[r][hd + 1] = f2bf(o1);
    xs[r][hd + 2] = f2bf(o2); xs[r][hd + 3] = f2bf(o3);
    *(float4*)&ysf[r][hd] = make_float4(o0, o1, o2, o3);
  }
  __syncthreads();
  const int ln = lane & 15, quad = lane >> 4;
  const int koff = quad * 8;
  bf16x8 a1[4];
#pragma unroll
  for (int kb = 0; kb < 4; kb++) a1[kb] = *(const bf16x8*)&xs[ln][kb * 32 + koff];
  for (int g = 0; g < 4; g++) {
    const int t0 = wv * 8 + g * 2;
    bf16x8 b[2][4];
#pragma unroll
    for (int j = 0; j < 2; j++)
#pragma unroll
      for (int kb = 0; kb < 4; kb++)
        b[j][kb] = *(const bf16x8*)&W1F[(size_t)(((t0 + j) * 4 + kb) * 64 + lane) * 8];
    f32x4 acc[2];
#pragma unroll
    for (int j = 0; j < 2; j++) acc[j] = (f32x4){0.f, 0.f, 0.f, 0.f};
#pragma unroll
    for (int kb = 0; kb < 4; kb++)
#pragma unroll
      for (int j = 0; j < 2; j++)
        acc[j] = __builtin_amdgcn_mfma_f32_16x16x32_bf16(a1[kb], b[j][kb], acc[j], 0, 0, 0);
#pragma unroll
    for (int j = 0; j < 2; j++) {
      const int col = (t0 + j) * 16 + ln;
      const float bias = b1[col];
#pragma unroll
      for (int r = 0; r < 4; r++)
        hs[quad * 4 + r][col] = f2bf(fmaxf(acc[j][r] + bias, 0.f));
    }
  }
  __syncthreads();
  f32x4 acc2[2];
  acc2[0] = (f32x4){0.f, 0.f, 0.f, 0.f};
  acc2[1] = (f32x4){0.f, 0.f, 0.f, 0.f};
  const int nt0 = wv * 2;
  for (int kg = 0; kg < 4; kg++) {
    bf16x8 a[4];
#pragma unroll
    for (int kk = 0; kk < 4; kk++)
      a[kk] = *(const bf16x8*)&hs[ln][(kg * 4 + kk) * 32 + koff];
    bf16x8 b[2][4];
#pragma unroll
    for (int nt = 0; nt < 2; nt++)
#pragma unroll
      for (int kk = 0; kk < 4; kk++)
        b[nt][kk] = *(const bf16x8*)&W2F[(size_t)(((nt0 + nt) * 16 + kg * 4 + kk) * 64 + lane) * 8];
#pragma unroll
    for (int kk = 0; kk < 4; kk++)
#pragma unroll
      for (int nt = 0; nt < 2; nt++)
        acc2[nt] = __builtin_amdgcn_mfma_f32_16x16x32_bf16(a[kk], b[nt][kk], acc2[nt], 0, 0, 0);
  }
  __syncthreads();
#pragma unroll
  for (int nt = 0; nt < 2; nt++) {
    const int col = (nt0 + nt) * 16 + ln;
    const float bias = b2[col];
#pragma unroll
    for (int r = 0; r < 4; r++)
      ys[(quad * 4 + r) * 132 + col] = acc2[nt][r] + bias;
  }
  __syncthreads();
  float2 gg = *(const float2*)&g2[2 * lane];
  float2 bbe = *(const float2*)&be2[2 * lane];
#pragma unroll
  for (int rr = 0; rr < 4; rr++) {
    const int r = wv * 4 + rr;
    const int row = row0 + r;
    float vx = ys[r * 132 + 2 * lane] + ysf[r][2 * lane];
    float vy = ys[r * 132 + 2 * lane + 1] + ysf[r][2 * lane + 1];
    float mean = wave_sum(vx + vy) * (1.f / ED);
    float dx = vx - mean, dy = vy - mean;
    float var = wave_sum(dx * dx + dy * dy) * (1.f / ED);
    float rstd = rsqrtf(var + 1e-5f);
    float2 o = make_float2(dx * rstd * gg.x + bbe.x, dy * rstd * gg.y + bbe.y);
    *(float2*)&out[(size_t)row * ED + 2 * lane] = o;
  }
}

extern "C" void kernel_launch(void* const* d_in, const int* in_sizes, int n_in,
                              void* d_out, int out_size, void* d_ws, size_t ws_size,
                              hipStream_t stream) {
  const float* x = (const float*)d_in[0];
  const int* ei = (const int*)d_in[1];
  const float* W_qkv = (const float*)d_in[2];
  const float* b_qkv = (const float*)d_in[3];
  const float* W1 = (const float*)d_in[4];
  const float* b1 = (const float*)d_in[5];
  const float* W2 = (const float*)d_in[6];
  const float* b2 = (const float*)d_in[7];
  const float* g1 = (const float*)d_in[8];
  const float* be1 = (const float*)d_in[9];
  const float* g2 = (const float*)d_in[10];
  const float* be2 = (const float*)d_in[11];
  float* out = (float*)d_out;

  char* ws = (char*)d_ws;
  size_t off = 0;
  auto alloc = [&](size_t bytes) -> char* {
    char* p = ws + off;
    off = (off + bytes + 255) & ~(size_t)255;
    return p;
  };
  unsigned short* q = (unsigned short*)alloc(2 * (size_t)NN * ED);
  unsigned short* kv = (unsigned short*)alloc(2 * (size_t)NN * 256);
  unsigned short* attb = (unsigned short*)alloc(2 * (size_t)NN * ED);
  unsigned short* WqkvF = (unsigned short*)alloc(2 * 24 * 4 * 64 * 8);
  unsigned short* W1F = (unsigned short*)alloc(2 * 32 * 4 * 64 * 8);
  unsigned short* W2F = (unsigned short*)alloc(2 * 8 * 16 * 64 * 8);
  int* cursor = (int*)alloc(sizeof(int) * NN);
  int* colidx = (int*)alloc(sizeof(int) * (size_t)NN * MAXDEG);

  k_prep<<<256, 256, 0, stream>>>(W_qkv, W1, W2, WqkvF, W1F, W2F, cursor);
  k_qkv_scat<<<QKV_BLOCKS + SCAT_BLOCKS, 256, 0, stream>>>(x, WqkvF, b_qkv, q, kv,
                                                           ei, ei + NE, cursor, colidx);
  k_attn<<<NN / 4, 256, 0, stream>>>(q, kv, x, cursor, colidx, attb);
  k_ffn_ln2<<<NN / 16, 256, 0, stream>>>(attb, W1F, b1, W2F, b2, g1, be1, g2, be2, out);
}

// Round 14
// 234.716 us; speedup vs baseline: 1.1889x; 1.0328x over previous
//
#include <hip/hip_runtime.h>
#include <math.h>

#define NN 50000
#define NE 800000
#define ED 128
#define FD 512
#define MAXDEG 64                           // P(Binom(800K,1/50K) > 64) ~ e^-40
#define CURS_STRIDE 16                      // one cursor per 64B line
#define QKV_BLOCKS (NN / 16)                // 3125
#define SCAT_BLOCKS ((NE + 255) / 256)      // 3125

typedef __attribute__((ext_vector_type(8))) short bf16x8;
typedef __attribute__((ext_vector_type(4))) float f32x4;
typedef _Float16 half2_t __attribute__((ext_vector_type(2)));

static __device__ __forceinline__ float wave_sum(float x) {
#pragma unroll
  for (int off = 32; off > 0; off >>= 1) x += __shfl_xor(x, off, 64);
  return x;
}

static __device__ __forceinline__ unsigned short f2bf(float f) {
  union { float f; unsigned u; } c; c.f = f;
  unsigned r = c.u + 0x7fffu + ((c.u >> 16) & 1u);
  return (unsigned short)(r >> 16);
}

static __device__ __forceinline__ unsigned short f2h(float f) {
  union { _Float16 h; unsigned short u; } c; c.h = (_Float16)f;
  return c.u;
}

static __device__ __forceinline__ half2_t u2h2(unsigned u) {
  union { unsigned u; half2_t h; } c; c.u = u;
  return c.h;
}

#if __has_builtin(__builtin_amdgcn_fdot2)
#define FDOT2(a, b, c) __builtin_amdgcn_fdot2((a), (b), (c), false)
#else
static __device__ __forceinline__ float FDOT2(half2_t a, half2_t b, float c) {
  return (float)a[0] * (float)b[0] + (float)a[1] * (float)b[1] + c;
}
#endif

// ---- one-time weight swizzle to fragment-major bf16 + cursor zero ----
__global__ void k_prep(const float* __restrict__ Wqkv, const float* __restrict__ W1,
                       const float* __restrict__ W2, unsigned short* __restrict__ WqkvF,
                       unsigned short* __restrict__ W1F, unsigned short* __restrict__ W2F,
                       int* __restrict__ cursor) {
  int idx = blockIdx.x * 256 + threadIdx.x;  // 65536 threads
  if (idx < NN) cursor[idx * CURS_STRIDE] = 0;
  if (idx < 49152) {  // WqkvF: t<24, kb<4
    int j = idx & 7, l = (idx >> 3) & 63, kb = (idx >> 9) & 3, t = idx >> 11;
    int k = kb * 32 + (l >> 4) * 8 + j, n = t * 16 + (l & 15);
    WqkvF[idx] = f2bf(Wqkv[k * 384 + n]);
  }
  {  // W1F: t<32, kb<4
    int j = idx & 7, l = (idx >> 3) & 63, kb = (idx >> 9) & 3, t = idx >> 11;
    int k = kb * 32 + (l >> 4) * 8 + j, n = t * 16 + (l & 15);
    W1F[idx] = f2bf(W1[k * 512 + n]);
  }
  {  // W2F: t<8, kb<16
    int j = idx & 7, l = (idx >> 3) & 63, kb = (idx >> 9) & 15, t = idx >> 13;
    int k = kb * 32 + (l >> 4) * 8 + j, n = t * 16 + (l & 15);
    W2F[idx] = f2bf(W2[k * 128 + n]);
  }
}

// ---- fused QKV GEMM + scatter, block-parity interleaved (r12-proven) ----
// This round's change: cursor padded to one per 64B line (was 16/line ->
// 256 serialized atomic RMWs per line at the owning L2 slice), and colidx
// stored as u16 (dst < 50000 < 65536) halving scatter store bytes.
__global__ __launch_bounds__(256) void k_qkv_scat(
    const float* __restrict__ X, const unsigned short* __restrict__ WqkvF,
    const float* __restrict__ B, unsigned short* __restrict__ q,
    unsigned short* __restrict__ kv, const int* __restrict__ src,
    const int* __restrict__ dst, int* __restrict__ cursor,
    unsigned short* __restrict__ colidx) {
  __shared__ unsigned short xs[16][136];
  const int tid = threadIdx.x;
  if (blockIdx.x & 1) {  // scatter half: odd blocks
    const int e = (blockIdx.x >> 1) * 256 + tid;
    if (e < NE) {
      const int s = src[e];
      const int d = dst[e];
      const int slot = atomicAdd(&cursor[s * CURS_STRIDE], 1);
      if (slot < MAXDEG) colidx[s * MAXDEG + slot] = (unsigned short)d;
    }
    return;
  }
  const int row0 = (blockIdx.x >> 1) * 16;
  for (int idx = tid; idx < 512; idx += 256) {
    int r = idx >> 5, c4 = (idx & 31) << 2;
    float4 val = *(const float4*)&X[(size_t)(row0 + r) * ED + c4];
    xs[r][c4] = f2bf(val.x); xs[r][c4 + 1] = f2bf(val.y);
    xs[r][c4 + 2] = f2bf(val.z); xs[r][c4 + 3] = f2bf(val.w);
  }
  __syncthreads();
  const int wv = tid >> 6, lane = tid & 63;
  const int ln = lane & 15, quad = lane >> 4;
  const int koff = quad * 8;
  bf16x8 a[4];
#pragma unroll
  for (int kb = 0; kb < 4; kb++) a[kb] = *(const bf16x8*)&xs[ln][kb * 32 + koff];
  for (int g = 0; g < 3; g++) {
    const int t0 = wv * 6 + g * 2;
    bf16x8 b[2][4];
#pragma unroll
    for (int j = 0; j < 2; j++)
#pragma unroll
      for (int kb = 0; kb < 4; kb++)
        b[j][kb] = *(const bf16x8*)&WqkvF[(size_t)(((t0 + j) * 4 + kb) * 64 + lane) * 8];
    f32x4 acc[2];
#pragma unroll
    for (int j = 0; j < 2; j++) acc[j] = (f32x4){0.f, 0.f, 0.f, 0.f};
#pragma unroll
    for (int kb = 0; kb < 4; kb++)
#pragma unroll
      for (int j = 0; j < 2; j++)
        acc[j] = __builtin_amdgcn_mfma_f32_16x16x32_bf16(a[kb], b[j][kb], acc[j], 0, 0, 0);
#pragma unroll
    for (int j = 0; j < 2; j++) {
      const int col = (t0 + j) * 16 + ln;
      const float bias = B[col];
      if (col < 128) {
#pragma unroll
        for (int r = 0; r < 4; r++)
          q[(size_t)(row0 + quad * 4 + r) * ED + col] =
              f2h((acc[j][r] + bias) * 0.08838834764831845f);  // 128^-0.5
      } else {
        // both K (col 128..255) and V (col 256..383) land at kv[row*256 + col-128]
#pragma unroll
        for (int r = 0; r < 4; r++)
          kv[(size_t)(row0 + quad * 4 + r) * 256 + (col - 128)] = f2h(acc[j][r] + bias);
      }
    }
  }
}

// ---- attention chunk (f16 packed math, r5-proven; u16 colidx) ----
template <bool FULL>
static __device__ __forceinline__ void attn_chunk(
    int base, int cnt, int grp, int gl, int lane, const half2_t* qh,
    const unsigned short* __restrict__ kv, const unsigned short* __restrict__ colidx,
    float& l, half2_t* axh) {
  const int C = FULL ? 16 : cnt;
  int colreg = 0;
  if (lane < C) colreg = colidx[base + lane];
  const int itmax = FULL ? 4 : ((C + 3) >> 2);
#pragma unroll(FULL ? 4 : 1)
  for (int it = 0; it < itmax; it++) {
    const int t = it * 4 + grp;
    const bool act = FULL || t < C;
    // inactive lanes re-load slot 0's row (valid, cache-hot, masked by e=0)
    const int cc = __shfl(colreg, act ? t : 0, 64);
    const unsigned short* row = &kv[(size_t)cc * 256 + gl * 8];
    uint4 kw = *(const uint4*)row;
    uint4 vw = *(const uint4*)(row + 128);  // imm offset:256 off same base
    float dot = FDOT2(qh[0], u2h2(kw.x), 0.f);
    dot = FDOT2(qh[1], u2h2(kw.y), dot);
    dot = FDOT2(qh[2], u2h2(kw.z), dot);
    dot = FDOT2(qh[3], u2h2(kw.w), dot);
    dot += __shfl_xor(dot, 1, 64);
    dot += __shfl_xor(dot, 2, 64);
    dot += __shfl_xor(dot, 4, 64);
    dot += __shfl_xor(dot, 8, 64);
    const float e = act ? __expf(dot) : 0.f;  // q pre-scaled by 128^-0.5
    l += e;
    const half2_t e2 = {(_Float16)e, (_Float16)e};
    axh[0] += e2 * u2h2(vw.x);
    axh[1] += e2 * u2h2(vw.y);
    axh[2] += e2 * u2h2(vw.z);
    axh[3] += e2 * u2h2(vw.w);
  }
}

// ---- attention on padded CSR: att = x + attn, stored f16 ----
__global__ __launch_bounds__(256) void k_attn(
    const unsigned short* __restrict__ q, const unsigned short* __restrict__ kv,
    const float* __restrict__ x, const int* __restrict__ cursor,
    const unsigned short* __restrict__ colidx, unsigned short* __restrict__ attb) {
  const int wv = threadIdx.x >> 6;
  const int lane = threadIdx.x & 63;
  const int grp = lane >> 4, gl = lane & 15;
  const int node = blockIdx.x * 4 + wv;  // NN % 4 == 0

  half2_t qh[4];
  {
    uint4 qw = *(const uint4*)&q[(size_t)node * ED + gl * 8];
    qh[0] = u2h2(qw.x); qh[1] = u2h2(qw.y);
    qh[2] = u2h2(qw.z); qh[3] = u2h2(qw.w);
  }
  const int cnt0 = cursor[node * CURS_STRIDE];
  const int cnt = cnt0 > MAXDEG ? MAXDEG : cnt0;
  const int b0 = node * MAXDEG;
  float l = 0.f;
  half2_t axh[4] = {};
  int off = 0;
  for (; off + 16 <= cnt; off += 16)
    attn_chunk<true>(b0 + off, 16, grp, gl, lane, qh, kv, colidx, l, axh);
  if (off < cnt)
    attn_chunk<false>(b0 + off, cnt - off, grp, gl, lane, qh, kv, colidx, l, axh);

  // cross-group reduction: groups hold disjoint edge subsets (packed halves)
#pragma unroll
  for (int j = 0; j < 4; j++) {
    union { half2_t h; int i; } c;
    union { int i; half2_t h; } d;
    c.h = axh[j]; d.i = __shfl_xor(c.i, 16, 64); axh[j] += d.h;
    c.h = axh[j]; d.i = __shfl_xor(c.i, 32, 64); axh[j] += d.h;
  }
  l += __shfl_xor(l, 16, 64);
  l += __shfl_xor(l, 32, 64);

  const float inv = (cnt > 0) ? 1.0f / l : 0.f;
  // this lane outputs dims d0, d0+1 (dims partitioned uniquely over 64 lanes)
  const int d0 = gl * 8 + grp * 2;
  const half2_t s = (grp == 0) ? axh[0] : (grp == 1) ? axh[1] : (grp == 2) ? axh[2] : axh[3];
  float2 xv = *(const float2*)&x[(size_t)node * ED + d0];
  unsigned pk = (unsigned)f2h(xv.x + (float)s[0] * inv) |
                ((unsigned)f2h(xv.y + (float)s[1] * inv) << 16);
  *(unsigned*)&attb[(size_t)node * ED + d0] = pk;
}

// ---- FFN via MFMA: LN1 (fused at staging) + FFN + residual + LN2 ----
// in: att f16 (x + attn); out: final f32   (r10-proven 16-row version)
__global__ __launch_bounds__(256) void k_ffn_ln2(
    const unsigned short* __restrict__ attb, const unsigned short* __restrict__ W1F,
    const float* __restrict__ b1, const unsigned short* __restrict__ W2F,
    const float* __restrict__ b2, const float* __restrict__ g1,
    const float* __restrict__ be1, const float* __restrict__ g2,
    const float* __restrict__ be2, float* __restrict__ out) {
  __shared__ unsigned short xs[16][136];
  __shared__ unsigned short hs[16][520];  // later aliased ys f32[16][132]
  __shared__ float ysf[16][132];          // LN1 output f32 (residual source)
  float* ys = (float*)&hs[0][0];
  const int row0 = blockIdx.x * 16;
  const int tid = threadIdx.x;
  {  // stage att f16 -> ysf f32: tid covers 8 halves (16B)
    const int r = tid >> 4, c8 = (tid & 15) << 3;
    uint4 aw = *(const uint4*)&attb[(size_t)(row0 + r) * ED + c8];
    half2_t h0 = u2h2(aw.x), h1 = u2h2(aw.y), h2 = u2h2(aw.z), h3 = u2h2(aw.w);
    ysf[r][c8] = (float)h0[0];     ysf[r][c8 + 1] = (float)h0[1];
    ysf[r][c8 + 2] = (float)h1[0]; ysf[r][c8 + 3] = (float)h1[1];
    ysf[r][c8 + 4] = (float)h2[0]; ysf[r][c8 + 5] = (float)h2[1];
    ysf[r][c8 + 6] = (float)h3[0]; ysf[r][c8 + 7] = (float)h3[1];
  }
  __syncthreads();
  const int wv = tid >> 6, lane = tid & 63;
  // LN1: each wave handles 4 rows in two passes (2 rows/pass, 32 lanes/row,
  // 4 dims/lane); covers all 16 rows: r = wv*4 + half*2 + (lane>>5).
#pragma unroll
  for (int half = 0; half < 2; half++) {
    const int r = wv * 4 + half * 2 + (lane >> 5);
    const int hd = (lane & 31) << 2;
    float4 vv = *(const float4*)&ysf[r][hd];
    float s4 = vv.x + vv.y + vv.z + vv.w;
#pragma unroll
    for (int off = 16; off > 0; off >>= 1) s4 += __shfl_xor(s4, off, 64);
    const float mean = s4 * (1.f / ED);
    const float dx0 = vv.x - mean, dx1 = vv.y - mean, dx2 = vv.z - mean, dx3 = vv.w - mean;
    float vr = dx0 * dx0 + dx1 * dx1 + dx2 * dx2 + dx3 * dx3;
#pragma unroll
    for (int off = 16; off > 0; off >>= 1) vr += __shfl_xor(vr, off, 64);
    const float rstd = rsqrtf(vr * (1.f / ED) + 1e-5f);
    const float4 gg = *(const float4*)&g1[hd];
    const float4 bb = *(const float4*)&be1[hd];
    const float o0 = dx0 * rstd * gg.x + bb.x;
    const float o1 = dx1 * rstd * gg.y + bb.y;
    const float o2 = dx2 * rstd * gg.z + bb.z;
    const float o3 = dx3 * rstd * gg.w + bb.w;
    xs[r][hd] = f2bf(o0); xs[r][hd + 1] = f2bf(o1);
    xs[r][hd + 2] = f2bf(o2); xs[r][hd + 3] = f2bf(o3);
    *(float4*)&ysf[r][hd] = make_float4(o0, o1, o2, o3);
  }
  __syncthreads();
  const int ln = lane & 15, quad = lane >> 4;
  const int koff = quad * 8;
  bf16x8 a1[4];
#pragma unroll
  for (int kb = 0; kb < 4; kb++) a1[kb] = *(const bf16x8*)&xs[ln][kb * 32 + koff];
  for (int g = 0; g < 4; g++) {
    const int t0 = wv * 8 + g * 2;
    bf16x8 b[2][4];
#pragma unroll
    for (int j = 0; j < 2; j++)
#pragma unroll
      for (int kb = 0; kb < 4; kb++)
        b[j][kb] = *(const bf16x8*)&W1F[(size_t)(((t0 + j) * 4 + kb) * 64 + lane) * 8];
    f32x4 acc[2];
#pragma unroll
    for (int j = 0; j < 2; j++) acc[j] = (f32x4){0.f, 0.f, 0.f, 0.f};
#pragma unroll
    for (int kb = 0; kb < 4; kb++)
#pragma unroll
      for (int j = 0; j < 2; j++)
        acc[j] = __builtin_amdgcn_mfma_f32_16x16x32_bf16(a1[kb], b[j][kb], acc[j], 0, 0, 0);
#pragma unroll
    for (int j = 0; j < 2; j++) {
      const int col = (t0 + j) * 16 + ln;
      const float bias = b1[col];
#pragma unroll
      for (int r = 0; r < 4; r++)
        hs[quad * 4 + r][col] = f2bf(fmaxf(acc[j][r] + bias, 0.f));
    }
  }
  __syncthreads();
  f32x4 acc2[2];
  acc2[0] = (f32x4){0.f, 0.f, 0.f, 0.f};
  acc2[1] = (f32x4){0.f, 0.f, 0.f, 0.f};
  const int nt0 = wv * 2;
  for (int kg = 0; kg < 4; kg++) {
    bf16x8 a[4];
#pragma unroll
    for (int kk = 0; kk < 4; kk++)
      a[kk] = *(const bf16x8*)&hs[ln][(kg * 4 + kk) * 32 + koff];
    bf16x8 b[2][4];
#pragma unroll
    for (int nt = 0; nt < 2; nt++)
#pragma unroll
      for (int kk = 0; kk < 4; kk++)
        b[nt][kk] = *(const bf16x8*)&W2F[(size_t)(((nt0 + nt) * 16 + kg * 4 + kk) * 64 + lane) * 8];
#pragma unroll
    for (int kk = 0; kk < 4; kk++)
#pragma unroll
      for (int nt = 0; nt < 2; nt++)
        acc2[nt] = __builtin_amdgcn_mfma_f32_16x16x32_bf16(a[kk], b[nt][kk], acc2[nt], 0, 0, 0);
  }
  __syncthreads();
#pragma unroll
  for (int nt = 0; nt < 2; nt++) {
    const int col = (nt0 + nt) * 16 + ln;
    const float bias = b2[col];
#pragma unroll
    for (int r = 0; r < 4; r++)
      ys[(quad * 4 + r) * 132 + col] = acc2[nt][r] + bias;
  }
  __syncthreads();
  float2 gg = *(const float2*)&g2[2 * lane];
  float2 bbe = *(const float2*)&be2[2 * lane];
#pragma unroll
  for (int rr = 0; rr < 4; rr++) {
    const int r = wv * 4 + rr;
    const int row = row0 + r;
    float vx = ys[r * 132 + 2 * lane] + ysf[r][2 * lane];
    float vy = ys[r * 132 + 2 * lane + 1] + ysf[r][2 * lane + 1];
    float mean = wave_sum(vx + vy) * (1.f / ED);
    float dx = vx - mean, dy = vy - mean;
    float var = wave_sum(dx * dx + dy * dy) * (1.f / ED);
    float rstd = rsqrtf(var + 1e-5f);
    float2 o = make_float2(dx * rstd * gg.x + bbe.x, dy * rstd * gg.y + bbe.y);
    *(float2*)&out[(size_t)row * ED + 2 * lane] = o;
  }
}

extern "C" void kernel_launch(void* const* d_in, const int* in_sizes, int n_in,
                              void* d_out, int out_size, void* d_ws, size_t ws_size,
                              hipStream_t stream) {
  const float* x = (const float*)d_in[0];
  const int* ei = (const int*)d_in[1];
  const float* W_qkv = (const float*)d_in[2];
  const float* b_qkv = (const float*)d_in[3];
  const float* W1 = (const float*)d_in[4];
  const float* b1 = (const float*)d_in[5];
  const float* W2 = (const float*)d_in[6];
  const float* b2 = (const float*)d_in[7];
  const float* g1 = (const float*)d_in[8];
  const float* be1 = (const float*)d_in[9];
  const float* g2 = (const float*)d_in[10];
  const float* be2 = (const float*)d_in[11];
  float* out = (float*)d_out;

  char* ws = (char*)d_ws;
  size_t off = 0;
  auto alloc = [&](size_t bytes) -> char* {
    char* p = ws + off;
    off = (off + bytes + 255) & ~(size_t)255;
    return p;
  };
  unsigned short* q = (unsigned short*)alloc(2 * (size_t)NN * ED);
  unsigned short* kv = (unsigned short*)alloc(2 * (size_t)NN * 256);
  unsigned short* attb = (unsigned short*)alloc(2 * (size_t)NN * ED);
  unsigned short* WqkvF = (unsigned short*)alloc(2 * 24 * 4 * 64 * 8);
  unsigned short* W1F = (unsigned short*)alloc(2 * 32 * 4 * 64 * 8);
  unsigned short* W2F = (unsigned short*)alloc(2 * 8 * 16 * 64 * 8);
  int* cursor = (int*)alloc(sizeof(int) * (size_t)NN * CURS_STRIDE);
  unsigned short* colidx = (unsigned short*)alloc(sizeof(unsigned short) * (size_t)NN * MAXDEG);

  k_prep<<<256, 256, 0, stream>>>(W_qkv, W1, W2, WqkvF, W1F, W2F, cursor);
  k_qkv_scat<<<QKV_BLOCKS + SCAT_BLOCKS, 256, 0, stream>>>(x, WqkvF, b_qkv, q, kv,
                                                           ei, ei + NE, cursor, colidx);
  k_attn<<<NN / 4, 256, 0, stream>>>(q, kv, x, cursor, colidx, attb);
  k_ffn_ln2<<<NN / 16, 256, 0, stream>>>(attb, W1F, b1, W2F, b2, g1, be1, g2, be2, out);
}